// Round 1
// baseline (1395.656 us; speedup 1.0000x reference)
//
#include <hip/hip_runtime.h>
#include <math.h>

#define DMODEL 1024
#define NHEADS 16
#define DK 64
#define BS 2
#define TS 2048
#define MROWS (BS * TS)   // 4096

// ---------------------------------------------------------------------------
// GEMM: C = A[M,K] @ W[N,K]^T + bias[N]
// BM=128, BN=64, BK=16, 256 threads (16x16), micro-tile TM=8 x TN=4.
// SCATTER=true writes C[m][n] into [B, H, T, DK] layout (for Q/K/V).
// ---------------------------------------------------------------------------
template <bool SCATTER>
__global__ __launch_bounds__(256) void gemm_bias_kernel(
    const float* __restrict__ A, const float* __restrict__ W,
    const float* __restrict__ bias, float* __restrict__ C,
    int M, int N, int K)
{
    __shared__ float As[16][132];  // [k][m], stride 132 floats = 16B-aligned
    __shared__ float Bs[16][68];   // [k][n]

    const int tid = threadIdx.x;
    const int ty = tid >> 4;        // 0..15 -> 8 rows each
    const int tx = tid & 15;        // 0..15 -> 4 cols each
    const int row0 = blockIdx.y * 128;
    const int col0 = blockIdx.x * 64;

    float acc[8][4];
#pragma unroll
    for (int i = 0; i < 8; ++i)
#pragma unroll
        for (int j = 0; j < 4; ++j) acc[i][j] = 0.f;

    const int ar = tid >> 2;         // 0..63
    const int ac = (tid & 3) << 2;   // 0,4,8,12

    for (int k0 = 0; k0 < K; k0 += 16) {
        // A tile: 128 x 16 (two passes of 64 rows), store transposed
#pragma unroll
        for (int p = 0; p < 2; ++p) {
            const int r = ar + (p << 6);
            const float4 av = *reinterpret_cast<const float4*>(
                &A[(size_t)(row0 + r) * K + k0 + ac]);
            As[ac + 0][r] = av.x; As[ac + 1][r] = av.y;
            As[ac + 2][r] = av.z; As[ac + 3][r] = av.w;
        }
        // W tile: 64 x 16, store transposed
        {
            const float4 wv = *reinterpret_cast<const float4*>(
                &W[(size_t)(col0 + ar) * K + k0 + ac]);
            Bs[ac + 0][ar] = wv.x; Bs[ac + 1][ar] = wv.y;
            Bs[ac + 2][ar] = wv.z; Bs[ac + 3][ar] = wv.w;
        }
        __syncthreads();

#pragma unroll
        for (int k = 0; k < 16; ++k) {
            float a[8], b[4];
            *reinterpret_cast<float4*>(&a[0]) =
                *reinterpret_cast<const float4*>(&As[k][(ty << 3) + 0]);
            *reinterpret_cast<float4*>(&a[4]) =
                *reinterpret_cast<const float4*>(&As[k][(ty << 3) + 4]);
            *reinterpret_cast<float4*>(&b[0]) =
                *reinterpret_cast<const float4*>(&Bs[k][tx << 2]);
#pragma unroll
            for (int i = 0; i < 8; ++i)
#pragma unroll
                for (int j = 0; j < 4; ++j)
                    acc[i][j] = fmaf(a[i], b[j], acc[i][j]);
        }
        __syncthreads();
    }

    // epilogue: bias + store
    const int n = col0 + (tx << 2);
    const float4 bv = *reinterpret_cast<const float4*>(&bias[n]);
#pragma unroll
    for (int i = 0; i < 8; ++i) {
        const int m = row0 + (ty << 3) + i;
        float4 cv;
        cv.x = acc[i][0] + bv.x;
        cv.y = acc[i][1] + bv.y;
        cv.z = acc[i][2] + bv.z;
        cv.w = acc[i][3] + bv.w;
        if (SCATTER) {
            // m -> (b, t), n -> (h, dk); dst layout [B, H, T, DK]
            const int bb = m >> 11;        // / 2048
            const int t  = m & 2047;
            const int h  = n >> 6;
            const int dk = n & 63;
            *reinterpret_cast<float4*>(
                &C[(((size_t)(bb * NHEADS + h) * TS + t) << 6) + dk]) = cv;
        } else {
            *reinterpret_cast<float4*>(&C[(size_t)m * N + n]) = cv;
        }
    }
}

// ---------------------------------------------------------------------------
// Flash-style attention: per block, 64 q-rows of one (b,h); iterate 64-key
// tiles with online softmax. 256 threads (16x16), 4x4 micro-tiles.
// Q/K/V in [B,H,T,DK]; ctx written in [B,T,DMODEL].
// ---------------------------------------------------------------------------
__global__ __launch_bounds__(256) void attn_kernel(
    const float* __restrict__ Q, const float* __restrict__ K,
    const float* __restrict__ V, float* __restrict__ ctx)
{
    __shared__ float QsT[64][68];  // [d][q]
    __shared__ float KsT[64][68];  // [d][s]
    __shared__ float Vs[64][68];   // [s][d]
    __shared__ float PsT[64][68];  // [s][q]

    const int tid = threadIdx.x;
    const int ty = tid >> 4;   // 0..15 -> 4 q-rows each
    const int tx = tid & 15;   // 0..15 -> 4 cols each
    const int bh = blockIdx.y;           // 0..31
    const int q0 = blockIdx.x << 6;
    const size_t base = (size_t)bh * TS * DK;
    const float* Qp = Q + base;
    const float* Kp = K + base;
    const float* Vp = V + base;

    const int lr = tid >> 4;           // 0..15, row within load pass
    const int lc = (tid & 15) << 2;    // 0..60

    // load Q tile transposed
#pragma unroll
    for (int p = 0; p < 4; ++p) {
        const int r = lr + (p << 4);
        const float4 qv = *reinterpret_cast<const float4*>(
            &Qp[(size_t)(q0 + r) * DK + lc]);
        QsT[lc + 0][r] = qv.x; QsT[lc + 1][r] = qv.y;
        QsT[lc + 2][r] = qv.z; QsT[lc + 3][r] = qv.w;
    }

    float m_i[4], l_i[4], o[4][4];
#pragma unroll
    for (int i = 0; i < 4; ++i) {
        m_i[i] = -1e30f;
        l_i[i] = 0.f;
#pragma unroll
        for (int j = 0; j < 4; ++j) o[i][j] = 0.f;
    }

    for (int s0 = 0; s0 < TS; s0 += 64) {
        __syncthreads();  // prev iteration's compute (and Q store) done
        // load K tile (transposed) + V tile (straight)
#pragma unroll
        for (int p = 0; p < 4; ++p) {
            const int r = lr + (p << 4);
            const float4 kv = *reinterpret_cast<const float4*>(
                &Kp[(size_t)(s0 + r) * DK + lc]);
            KsT[lc + 0][r] = kv.x; KsT[lc + 1][r] = kv.y;
            KsT[lc + 2][r] = kv.z; KsT[lc + 3][r] = kv.w;
            *reinterpret_cast<float4*>(&Vs[r][lc]) =
                *reinterpret_cast<const float4*>(&Vp[(size_t)(s0 + r) * DK + lc]);
        }
        __syncthreads();

        // S = (Q @ K^T) / 8
        float s[4][4];
#pragma unroll
        for (int i = 0; i < 4; ++i)
#pragma unroll
            for (int j = 0; j < 4; ++j) s[i][j] = 0.f;
#pragma unroll
        for (int d = 0; d < 64; ++d) {
            float a[4], b[4];
            *reinterpret_cast<float4*>(a) =
                *reinterpret_cast<const float4*>(&QsT[d][ty << 2]);
            *reinterpret_cast<float4*>(b) =
                *reinterpret_cast<const float4*>(&KsT[d][tx << 2]);
#pragma unroll
            for (int i = 0; i < 4; ++i)
#pragma unroll
                for (int j = 0; j < 4; ++j)
                    s[i][j] = fmaf(a[i], b[j], s[i][j]);
        }
#pragma unroll
        for (int i = 0; i < 4; ++i)
#pragma unroll
            for (int j = 0; j < 4; ++j) s[i][j] *= 0.125f;

        // online softmax: row max across the 16 lanes sharing each row group
        float mt[4];
#pragma unroll
        for (int i = 0; i < 4; ++i)
            mt[i] = fmaxf(fmaxf(s[i][0], s[i][1]), fmaxf(s[i][2], s[i][3]));
#pragma unroll
        for (int off = 1; off < 16; off <<= 1)
#pragma unroll
            for (int i = 0; i < 4; ++i)
                mt[i] = fmaxf(mt[i], __shfl_xor(mt[i], off));

        float p4[4][4], rs[4];
#pragma unroll
        for (int i = 0; i < 4; ++i) {
            const float mn = fmaxf(m_i[i], mt[i]);
            const float f = expf(m_i[i] - mn);
            m_i[i] = mn;
            float r = 0.f;
#pragma unroll
            for (int j = 0; j < 4; ++j) {
                p4[i][j] = expf(s[i][j] - mn);
                r += p4[i][j];
            }
            rs[i] = r;
            l_i[i] *= f;
#pragma unroll
            for (int j = 0; j < 4; ++j) o[i][j] *= f;
        }
#pragma unroll
        for (int off = 1; off < 16; off <<= 1)
#pragma unroll
            for (int i = 0; i < 4; ++i)
                rs[i] += __shfl_xor(rs[i], off);
#pragma unroll
        for (int i = 0; i < 4; ++i) l_i[i] += rs[i];

        // P into LDS (transposed: [s][q])
#pragma unroll
        for (int i = 0; i < 4; ++i)
#pragma unroll
            for (int j = 0; j < 4; ++j)
                PsT[(tx << 2) + j][(ty << 2) + i] = p4[i][j];
        __syncthreads();

        // O += P @ V
#pragma unroll
        for (int ss = 0; ss < 64; ++ss) {
            float a[4], b[4];
            *reinterpret_cast<float4*>(a) =
                *reinterpret_cast<const float4*>(&PsT[ss][ty << 2]);
            *reinterpret_cast<float4*>(b) =
                *reinterpret_cast<const float4*>(&Vs[ss][tx << 2]);
#pragma unroll
            for (int i = 0; i < 4; ++i)
#pragma unroll
                for (int j = 0; j < 4; ++j)
                    o[i][j] = fmaf(a[i], b[j], o[i][j]);
        }
    }

    // normalize + write ctx in [B, T, DMODEL]
    const int bb = bh >> 4;
    const int h = bh & 15;
#pragma unroll
    for (int i = 0; i < 4; ++i) {
        const int t = q0 + (ty << 2) + i;
        const float inv = 1.0f / l_i[i];
        float4 cv;
        cv.x = o[i][0] * inv;
        cv.y = o[i][1] * inv;
        cv.z = o[i][2] * inv;
        cv.w = o[i][3] * inv;
        *reinterpret_cast<float4*>(
            &ctx[(size_t)(bb * TS + t) * DMODEL + h * 64 + (tx << 2)]) = cv;
    }
}

// ---------------------------------------------------------------------------
extern "C" void kernel_launch(void* const* d_in, const int* in_sizes, int n_in,
                              void* d_out, int out_size, void* d_ws, size_t ws_size,
                              hipStream_t stream)
{
    const float* query  = (const float*)d_in[0];
    const float* key_in = (const float*)d_in[1];
    const float* value  = (const float*)d_in[2];
    const float* Wq = (const float*)d_in[3];
    const float* bq = (const float*)d_in[4];
    const float* Wk = (const float*)d_in[5];
    const float* bk = (const float*)d_in[6];
    const float* Wv = (const float*)d_in[7];
    const float* bv = (const float*)d_in[8];
    const float* Wo = (const float*)d_in[9];
    const float* bo = (const float*)d_in[10];
    float* out = (float*)d_out;

    float* ws = (float*)d_ws;
    const size_t tsz = (size_t)MROWS * DMODEL;  // 4 MiB elements = 16 MiB
    float* qb = ws;
    float* kb = ws + tsz;
    float* vb = ws + 2 * tsz;
    float* cb = ws + 3 * tsz;

    const dim3 gg(DMODEL / 64, MROWS / 128);  // (16, 32) = 512 blocks
    gemm_bias_kernel<true><<<gg, 256, 0, stream>>>(query,  Wq, bq, qb, MROWS, DMODEL, DMODEL);
    gemm_bias_kernel<true><<<gg, 256, 0, stream>>>(key_in, Wk, bk, kb, MROWS, DMODEL, DMODEL);
    gemm_bias_kernel<true><<<gg, 256, 0, stream>>>(value,  Wv, bv, vb, MROWS, DMODEL, DMODEL);
    attn_kernel<<<dim3(TS / 64, BS * NHEADS), 256, 0, stream>>>(qb, kb, vb, cb);
    gemm_bias_kernel<false><<<gg, 256, 0, stream>>>(cb, Wo, bo, out, MROWS, DMODEL, DMODEL);
}

// Round 2
// 328.205 us; speedup vs baseline: 4.2524x; 4.2524x over previous
//
#include <hip/hip_runtime.h>

typedef unsigned short ushort_t;
typedef __attribute__((ext_vector_type(8))) short bf16x8;
typedef __attribute__((ext_vector_type(4))) float f32x4;

#define DMODEL 1024
#define NHEADS 16
#define DK 64
#define BS 2
#define TS 2048
#define MROWS (BS * TS)  // 4096

__device__ __forceinline__ ushort_t f2bf(float x) {
    unsigned u = __float_as_uint(x);
    unsigned r = (u + 0x7FFFu + ((u >> 16) & 1u)) >> 16;  // RNE
    return (ushort_t)r;
}

__device__ __forceinline__ void gload_lds16(const void* g, void* l) {
    __builtin_amdgcn_global_load_lds(
        (const __attribute__((address_space(1))) unsigned int*)g,
        (__attribute__((address_space(3))) unsigned int*)l, 16, 0, 0);
}

// ---------------------------------------------------------------------------
// fp32 -> bf16 cast of the 3 activations (4M elems each) + 4 weights (1M each)
// into one contiguous 32MB bf16 region. One float4 per thread.
// ---------------------------------------------------------------------------
__global__ __launch_bounds__(256) void cvt_all_kernel(
    const float* __restrict__ q, const float* __restrict__ k,
    const float* __restrict__ v, const float* __restrict__ wq,
    const float* __restrict__ wk, const float* __restrict__ wv,
    const float* __restrict__ wo, ushort_t* __restrict__ dst)
{
    const int i = blockIdx.x * 256 + threadIdx.x;  // float4 index, 0..4M-1
    const float4* s;
    int off;
    if (i < (1 << 20))      { s = (const float4*)q; off = i; }
    else if (i < (2 << 20)) { s = (const float4*)k; off = i - (1 << 20); }
    else if (i < (3 << 20)) { s = (const float4*)v; off = i - (2 << 20); }
    else {
        const int j = i - (3 << 20);
        const int w = j >> 18;
        off = j & 0x3FFFF;
        s = (w == 0) ? (const float4*)wq : (w == 1) ? (const float4*)wk
          : (w == 2) ? (const float4*)wv : (const float4*)wo;
    }
    const float4 x = s[off];
    ushort4 o;
    o.x = f2bf(x.x); o.y = f2bf(x.y); o.z = f2bf(x.z); o.w = f2bf(x.w);
    ((ushort4*)dst)[i] = o;
}

// ---------------------------------------------------------------------------
// bf16 MFMA GEMM: C = A[4096,1024] @ W[1024,1024]^T + bias
// BM=128 BN=64 BK=32, 256 thr (4 waves), wave tile 64x32 (4x2 frags 16x16).
// MODE 0: fp32 out [M][N].  MODE 1: bf16 out scattered to [B,H,T,DK].
// ---------------------------------------------------------------------------
template <int MODE>
__global__ __launch_bounds__(256) void gemm_bf16_kernel(
    const ushort_t* __restrict__ A, const ushort_t* __restrict__ W,
    const float* __restrict__ bias, void* __restrict__ Cout)
{
    __shared__ ushort_t Asm[128 * 32];
    __shared__ ushort_t Bsm[64 * 32];

    const int tid = threadIdx.x;
    const int w = tid >> 6;
    const int lane = tid & 63;
    const int c = lane & 15;     // frag row/col within 16
    const int g = lane >> 4;     // k-group
    const int row0 = blockIdx.y * 128;
    const int col0 = blockIdx.x * 64;
    const int wr = w >> 1, wc = w & 1;  // wave tile origin: rows wr*64, cols wc*32

    f32x4 acc[4][2];
#pragma unroll
    for (int m = 0; m < 4; ++m)
#pragma unroll
        for (int n = 0; n < 2; ++n) acc[m][n] = (f32x4){0.f, 0.f, 0.f, 0.f};

    const int lr = lane >> 2;          // staging row 0..15 within a 16-row chunk
    const int lcb = (lane & 3) * 8;    // ushort offset (16B chunks)

    for (int k0 = 0; k0 < DMODEL; k0 += 32) {
        // async stage: wave w -> A rows [w*32, +32) (2 instr), B rows [w*16, +16)
        gload_lds16(&A[(size_t)(row0 + w * 32 + lr) * DMODEL + k0 + lcb],
                    &Asm[(w * 32) * 32]);
        gload_lds16(&A[(size_t)(row0 + w * 32 + 16 + lr) * DMODEL + k0 + lcb],
                    &Asm[(w * 32 + 16) * 32]);
        gload_lds16(&W[(size_t)(col0 + w * 16 + lr) * DMODEL + k0 + lcb],
                    &Bsm[(w * 16) * 32]);
        __syncthreads();  // drains vmcnt before barrier

        bf16x8 a[4], b[2];
#pragma unroll
        for (int m = 0; m < 4; ++m)
            a[m] = *(const bf16x8*)&Asm[(wr * 64 + m * 16 + c) * 32 + g * 8];
#pragma unroll
        for (int n = 0; n < 2; ++n)
            b[n] = *(const bf16x8*)&Bsm[(wc * 32 + n * 16 + c) * 32 + g * 8];
#pragma unroll
        for (int m = 0; m < 4; ++m)
#pragma unroll
            for (int n = 0; n < 2; ++n)
                acc[m][n] = __builtin_amdgcn_mfma_f32_16x16x32_bf16(
                    a[m], b[n], acc[m][n], 0, 0, 0);
        __syncthreads();
    }

    // epilogue: C/D layout col=lane&15, row=(lane>>4)*4+reg  [m89 verified]
    const int gc0 = col0 + wc * 32;
    const float bv[2] = {bias[gc0 + c], bias[gc0 + 16 + c]};
#pragma unroll
    for (int m = 0; m < 4; ++m) {
#pragma unroll
        for (int n = 0; n < 2; ++n) {
            const int gc = gc0 + n * 16 + c;
#pragma unroll
            for (int r = 0; r < 4; ++r) {
                const int gr = row0 + wr * 64 + m * 16 + g * 4 + r;
                const float val = acc[m][n][r] + bv[n];
                if (MODE == 0) {
                    ((float*)Cout)[(size_t)gr * DMODEL + gc] = val;
                } else {
                    const int bb = gr >> 11, t = gr & 2047;
                    const int h = gc >> 6, dk = gc & 63;
                    ((ushort_t*)Cout)[(((size_t)(bb * NHEADS + h) * TS + t) << 6) + dk] =
                        f2bf(val);
                }
            }
        }
    }
}

// ---------------------------------------------------------------------------
// bf16 MFMA flash attention. Block = 4 waves, QBLK=64 (16 q-rows/wave),
// KV tiles of 64. K/V^T/P tiles in LDS with XOR swizzle byte^=((row&7)<<4)
// so all fragment ds_read_b128 are conflict-free. Online softmax fully
// wave-parallel in the C-fragment layout. ctx out bf16 [B,T,DMODEL].
// ---------------------------------------------------------------------------
__global__ __launch_bounds__(256) void attn_bf16_kernel(
    const ushort_t* __restrict__ Q, const ushort_t* __restrict__ K,
    const ushort_t* __restrict__ V, ushort_t* __restrict__ ctx)
{
    __shared__ ushort_t Ks[64 * 64];      // [s][d] swizzled, 8KB
    __shared__ ushort_t Vt[64 * 64];      // [d][s] swizzled, 8KB
    __shared__ ushort_t Ps[4][16 * 64];   // per-wave [q][s] swizzled, 8KB

    const int tid = threadIdx.x;
    const int w = tid >> 6;
    const int lane = tid & 63;
    const int c = lane & 15;
    const int g = lane >> 4;
    const int bh = blockIdx.y;
    const int q0 = blockIdx.x * 64;
    const size_t base = (size_t)bh * TS * DK;
    const ushort_t* Qp = Q + base + (size_t)(q0 + w * 16) * DK;
    const ushort_t* Kp = K + base;
    const ushort_t* Vp = V + base;

    // Q fragments held in registers: lane (c + 16g), rows = c, k = ch*32+g*8+j
    bf16x8 qa[2];
    qa[0] = *(const bf16x8*)&Qp[c * DK + g * 8];
    qa[1] = *(const bf16x8*)&Qp[c * DK + 32 + g * 8];

    float m_i[4], l_i[4];
    f32x4 o[4];
#pragma unroll
    for (int r = 0; r < 4; ++r) { m_i[r] = -1e30f; l_i[r] = 0.f; }
#pragma unroll
    for (int df = 0; df < 4; ++df) o[df] = (f32x4){0.f, 0.f, 0.f, 0.f};

    const int sv = tid >> 2;   // staging row 0..63
    const int c4 = tid & 3;    // 16-elem column chunk

    for (int s0 = 0; s0 < TS; s0 += 64) {
        __syncthreads();  // prev tile's compute done before overwrite
        {
            // K tile: row sv, 32B chunk
            const ushort_t* kg = &Kp[(size_t)(s0 + sv) * DK + c4 * 16];
            const bf16x8 k0v = *(const bf16x8*)kg;
            const bf16x8 k1v = *(const bf16x8*)(kg + 8);
            char* krow = (char*)Ks + sv * 128;
            const int ksw = (sv & 7) << 4;
            *(bf16x8*)(krow + ((c4 * 32 + 0) ^ ksw)) = k0v;
            *(bf16x8*)(krow + ((c4 * 32 + 16) ^ ksw)) = k1v;
            // V tile transposed into Vt[d][s]
            const ushort_t* vg = &Vp[(size_t)(s0 + sv) * DK + c4 * 16];
            const bf16x8 v0v = *(const bf16x8*)vg;
            const bf16x8 v1v = *(const bf16x8*)(vg + 8);
#pragma unroll
            for (int j = 0; j < 8; ++j) {
                const int d = c4 * 16 + j;
                *(ushort_t*)((char*)Vt + d * 128 + ((2 * sv) ^ ((d & 7) << 4))) =
                    (ushort_t)v0v[j];
            }
#pragma unroll
            for (int j = 0; j < 8; ++j) {
                const int d = c4 * 16 + 8 + j;
                *(ushort_t*)((char*)Vt + d * 128 + ((2 * sv) ^ ((d & 7) << 4))) =
                    (ushort_t)v1v[j];
            }
        }
        __syncthreads();

        // S = Q @ K^T  (4 col-frags of 16 s each, k = DK in 2 chunks)
        f32x4 sf[4];
#pragma unroll
        for (int fc = 0; fc < 4; ++fc) sf[fc] = (f32x4){0.f, 0.f, 0.f, 0.f};
#pragma unroll
        for (int fc = 0; fc < 4; ++fc) {
            const int srow = fc * 16 + c;
            const int ssw = (srow & 7) << 4;
#pragma unroll
            for (int ch = 0; ch < 2; ++ch) {
                const bf16x8 kb = *(const bf16x8*)((char*)Ks + srow * 128 +
                                                   ((ch * 64 + g * 16) ^ ssw));
                sf[fc] = __builtin_amdgcn_mfma_f32_16x16x32_bf16(qa[ch], kb, sf[fc],
                                                                 0, 0, 0);
            }
        }

        // online softmax (rows = g*4+r, replicated across the 16 lanes c)
        float mt[4];
#pragma unroll
        for (int r = 0; r < 4; ++r)
            mt[r] = fmaxf(fmaxf(sf[0][r], sf[1][r]), fmaxf(sf[2][r], sf[3][r]));
#pragma unroll
        for (int off = 1; off < 16; off <<= 1)
#pragma unroll
            for (int r = 0; r < 4; ++r)
                mt[r] = fmaxf(mt[r], __shfl_xor(mt[r], off));

        float mn[4], f[4], p[4][4], rs[4];
#pragma unroll
        for (int r = 0; r < 4; ++r) {
            mn[r] = fmaxf(m_i[r], mt[r]);
            f[r] = __expf((m_i[r] - mn[r]) * 0.125f);
            m_i[r] = mn[r];
        }
#pragma unroll
        for (int fc = 0; fc < 4; ++fc)
#pragma unroll
            for (int r = 0; r < 4; ++r)
                p[fc][r] = __expf((sf[fc][r] - mn[r]) * 0.125f);
#pragma unroll
        for (int r = 0; r < 4; ++r)
            rs[r] = (p[0][r] + p[1][r]) + (p[2][r] + p[3][r]);
#pragma unroll
        for (int off = 1; off < 16; off <<= 1)
#pragma unroll
            for (int r = 0; r < 4; ++r) rs[r] += __shfl_xor(rs[r], off);
#pragma unroll
        for (int r = 0; r < 4; ++r) l_i[r] = l_i[r] * f[r] + rs[r];
#pragma unroll
        for (int df = 0; df < 4; ++df)
#pragma unroll
            for (int r = 0; r < 4; ++r) o[df][r] *= f[r];

        // P -> per-wave LDS (bf16, swizzled). Same-wave DS ops are in-order.
        char* Pw = (char*)&Ps[w][0];
#pragma unroll
        for (int r = 0; r < 4; ++r) {
            const int prow = g * 4 + r;
            char* prp = Pw + prow * 128;
            const int psw = (prow & 7) << 4;
#pragma unroll
            for (int fc = 0; fc < 4; ++fc)
                *(ushort_t*)(prp + ((2 * (fc * 16 + c)) ^ psw)) = f2bf(p[fc][r]);
        }

        // O += P @ V
#pragma unroll
        for (int ch = 0; ch < 2; ++ch) {
            const bf16x8 pa = *(const bf16x8*)(Pw + c * 128 +
                                               ((ch * 64 + g * 16) ^ ((c & 7) << 4)));
#pragma unroll
            for (int df = 0; df < 4; ++df) {
                const int vrow = df * 16 + c;
                const bf16x8 vb = *(const bf16x8*)((char*)Vt + vrow * 128 +
                                                   ((ch * 64 + g * 16) ^ ((vrow & 7) << 4)));
                o[df] = __builtin_amdgcn_mfma_f32_16x16x32_bf16(pa, vb, o[df], 0, 0, 0);
            }
        }
    }

    // epilogue: normalize, write ctx bf16 [B,T,DMODEL]
    const int bb = bh >> 4, h = bh & 15;
#pragma unroll
    for (int r = 0; r < 4; ++r) {
        const float inv = 1.0f / l_i[r];
        const int t = q0 + w * 16 + g * 4 + r;
        const size_t rowb = ((size_t)(bb * TS + t)) * DMODEL + h * 64;
#pragma unroll
        for (int df = 0; df < 4; ++df)
            ctx[rowb + df * 16 + c] = f2bf(o[df][r] * inv);
    }
}

// ---------------------------------------------------------------------------
extern "C" void kernel_launch(void* const* d_in, const int* in_sizes, int n_in,
                              void* d_out, int out_size, void* d_ws, size_t ws_size,
                              hipStream_t stream)
{
    const float* query  = (const float*)d_in[0];
    const float* key_in = (const float*)d_in[1];
    const float* value  = (const float*)d_in[2];
    const float* Wq = (const float*)d_in[3];
    const float* bq = (const float*)d_in[4];
    const float* Wk = (const float*)d_in[5];
    const float* bk = (const float*)d_in[6];
    const float* Wv = (const float*)d_in[7];
    const float* bv = (const float*)d_in[8];
    const float* Wo = (const float*)d_in[9];
    const float* bo = (const float*)d_in[10];

    ushort_t* W16 = (ushort_t*)d_ws;
    const size_t M1 = 1u << 20;
    ushort_t* qi  = W16;             // bf16 activations: 4M elems each
    ushort_t* ki  = W16 + 4 * M1;
    ushort_t* vi  = W16 + 8 * M1;
    ushort_t* wqb = W16 + 12 * M1;   // bf16 weights: 1M elems each
    ushort_t* wkb = W16 + 13 * M1;
    ushort_t* wvb = W16 + 14 * M1;
    ushort_t* wob = W16 + 15 * M1;
    ushort_t* Qp  = W16 + 16 * M1;   // projected [B,H,T,DK] bf16
    ushort_t* Kp  = W16 + 20 * M1;
    ushort_t* Vp  = W16 + 24 * M1;
    ushort_t* cb  = W16 + 28 * M1;   // ctx bf16 [B,T,DMODEL]

    cvt_all_kernel<<<16384, 256, 0, stream>>>(query, key_in, value, Wq, Wk, Wv, Wo, W16);

    const dim3 gg(DMODEL / 64, MROWS / 128);  // (16, 32) = 512 blocks
    gemm_bf16_kernel<1><<<gg, 256, 0, stream>>>(qi, wqb, bq, Qp);
    gemm_bf16_kernel<1><<<gg, 256, 0, stream>>>(ki, wkb, bk, Kp);
    gemm_bf16_kernel<1><<<gg, 256, 0, stream>>>(vi, wvb, bv, Vp);
    attn_bf16_kernel<<<dim3(TS / 64, BS * NHEADS), 256, 0, stream>>>(Qp, Kp, Vp, cb);
    gemm_bf16_kernel<0><<<gg, 256, 0, stream>>>(cb, wob, bo, (float*)d_out);
}

// Round 3
// 266.848 us; speedup vs baseline: 5.2302x; 1.2299x over previous
//
#include <hip/hip_runtime.h>

typedef unsigned short ushort_t;
typedef __attribute__((ext_vector_type(8))) short bf16x8;
typedef __attribute__((ext_vector_type(4))) float f32x4;

#define DMODEL 1024
#define NHEADS 16
#define DK 64
#define BS 2
#define TS 2048
#define MROWS (BS * TS)  // 4096

__device__ __forceinline__ ushort_t f2bf(float x) {
    unsigned u = __float_as_uint(x);
    return (ushort_t)((u + 0x7FFFu + ((u >> 16) & 1u)) >> 16);  // RNE
}

__device__ __forceinline__ unsigned cvt_pk_bf16(float lo, float hi) {
    unsigned r;
    asm("v_cvt_pk_bf16_f32 %0, %1, %2" : "=v"(r) : "v"(lo), "v"(hi));
    return r;
}

__device__ __forceinline__ void gload_lds16(const void* g, void* l) {
    __builtin_amdgcn_global_load_lds(
        (const __attribute__((address_space(1))) unsigned*)g,
        (__attribute__((address_space(3))) unsigned*)l, 16, 0, 0);
}

// ---------------------------------------------------------------------------
// fp32 -> bf16 cast: 3 activations (4M each) + 4 weights (1M each).
// ---------------------------------------------------------------------------
__global__ __launch_bounds__(256) void cvt_all_kernel(
    const float* __restrict__ q, const float* __restrict__ k,
    const float* __restrict__ v, const float* __restrict__ wq,
    const float* __restrict__ wk, const float* __restrict__ wv,
    const float* __restrict__ wo, ushort_t* __restrict__ dst)
{
    const int i = blockIdx.x * 256 + threadIdx.x;  // float4 index
    const float4* s;
    int off;
    if (i < (1 << 20))      { s = (const float4*)q; off = i; }
    else if (i < (2 << 20)) { s = (const float4*)k; off = i - (1 << 20); }
    else if (i < (3 << 20)) { s = (const float4*)v; off = i - (2 << 20); }
    else {
        const int j = i - (3 << 20);
        const int w = j >> 18;
        off = j & 0x3FFFF;
        s = (w == 0) ? (const float4*)wq : (w == 1) ? (const float4*)wk
          : (w == 2) ? (const float4*)wv : (const float4*)wo;
    }
    const float4 x = s[off];
    ushort4 o;
    o.x = f2bf(x.x); o.y = f2bf(x.y); o.z = f2bf(x.z); o.w = f2bf(x.w);
    ((ushort4*)dst)[i] = o;
}

// ---------------------------------------------------------------------------
// Shared GEMM core: acc = A[128 rows] @ W[64 rows]^T over K=1024.
// BK=32, double-buffered LDS, single barrier per k-step (stage next ->
// compute cur -> __syncthreads drains vmcnt+lgkm).
// 64B LDS rows (32 bf16) are naturally conflict-free for frag reads.
// ---------------------------------------------------------------------------
__device__ __forceinline__ void gemm_body(
    const ushort_t* __restrict__ A, const ushort_t* __restrict__ W,
    ushort_t (&Asm)[2][4096], ushort_t (&Bsm)[2][2048],
    f32x4 (&acc)[4][2], int row0, int col0, int w, int lane)
{
    const int c = lane & 15, g = lane >> 4;
    const int wr = w >> 1, wc = w & 1;
    const int lr = lane >> 2;          // 0..15 staging row within 16-chunk
    const int lcb = (lane & 3) * 8;    // 16B chunk within 64B row
    const ushort_t* Ab = &A[(size_t)(row0 + w * 32 + lr) * DMODEL + lcb];
    const ushort_t* Wb = &W[(size_t)(col0 + w * 16 + lr) * DMODEL + lcb];

#define GSTAGE(buf, k0_) do { \
    gload_lds16(Ab + (k0_), &Asm[buf][(w * 32) * 32]); \
    gload_lds16(Ab + 16 * DMODEL + (k0_), &Asm[buf][(w * 32 + 16) * 32]); \
    gload_lds16(Wb + (k0_), &Bsm[buf][(w * 16) * 32]); \
} while (0)

    GSTAGE(0, 0);
    __syncthreads();
    int cur = 0;
    for (int k0 = 0; k0 < DMODEL; k0 += 32) {
        if (k0 + 32 < DMODEL) GSTAGE(cur ^ 1, k0 + 32);
        bf16x8 a[4], b[2];
#pragma unroll
        for (int m = 0; m < 4; ++m)
            a[m] = *(const bf16x8*)&Asm[cur][(wr * 64 + m * 16 + c) * 32 + g * 8];
#pragma unroll
        for (int n = 0; n < 2; ++n)
            b[n] = *(const bf16x8*)&Bsm[cur][(wc * 32 + n * 16 + c) * 32 + g * 8];
#pragma unroll
        for (int m = 0; m < 4; ++m)
#pragma unroll
            for (int n = 0; n < 2; ++n)
                acc[m][n] = __builtin_amdgcn_mfma_f32_16x16x32_bf16(
                    a[m], b[n], acc[m][n], 0, 0, 0);
        __syncthreads();
        cur ^= 1;
    }
#undef GSTAGE
}

// ---------------------------------------------------------------------------
// Fused QKV projections. z=0: Q -> [B,H,T,DK] *0.125 ; z=1: K -> [B,H,T,DK];
// z=2: V -> transposed [B,H,DK,T] (packed 8B stores along t).
// ---------------------------------------------------------------------------
__global__ __launch_bounds__(256) void gemm_qkv_kernel(
    const ushort_t* __restrict__ Aq, const ushort_t* __restrict__ Ak,
    const ushort_t* __restrict__ Av, const ushort_t* __restrict__ Wq,
    const ushort_t* __restrict__ Wk, const ushort_t* __restrict__ Wv,
    const float* __restrict__ bq, const float* __restrict__ bk,
    const float* __restrict__ bv, ushort_t* __restrict__ Qo,
    ushort_t* __restrict__ Ko, ushort_t* __restrict__ VTo)
{
    __shared__ ushort_t Asm[2][4096];
    __shared__ ushort_t Bsm[2][2048];

    const int z = blockIdx.z;
    const ushort_t* A = (z == 0) ? Aq : (z == 1) ? Ak : Av;
    const ushort_t* W = (z == 0) ? Wq : (z == 1) ? Wk : Wv;
    const float* bias = (z == 0) ? bq : (z == 1) ? bk : bv;
    const float scale = (z == 0) ? 0.125f : 1.0f;

    const int tid = threadIdx.x, w = tid >> 6, lane = tid & 63;
    const int c = lane & 15, g = lane >> 4;
    const int wr = w >> 1, wc = w & 1;
    const int row0 = blockIdx.y * 128, col0 = blockIdx.x * 64;

    f32x4 acc[4][2];
#pragma unroll
    for (int m = 0; m < 4; ++m)
#pragma unroll
        for (int n = 0; n < 2; ++n) acc[m][n] = (f32x4){0.f, 0.f, 0.f, 0.f};

    gemm_body(A, W, Asm, Bsm, acc, row0, col0, w, lane);

    const int gc0 = col0 + wc * 32;
    const float bv2[2] = {bias[gc0 + c], bias[gc0 + 16 + c]};
    if (z < 2) {
        ushort_t* O = (z == 0) ? Qo : Ko;
#pragma unroll
        for (int m = 0; m < 4; ++m)
#pragma unroll
            for (int n = 0; n < 2; ++n) {
                const int gc = gc0 + n * 16 + c;
                const int h = gc >> 6, dk = gc & 63;
#pragma unroll
                for (int r = 0; r < 4; ++r) {
                    const int gr = row0 + wr * 64 + m * 16 + g * 4 + r;
                    const int bb = gr >> 11, t = gr & 2047;
                    O[(((size_t)(bb * NHEADS + h) * TS + t) << 6) + dk] =
                        f2bf((acc[m][n][r] + bv2[n]) * scale);
                }
            }
    } else {
#pragma unroll
        for (int m = 0; m < 4; ++m) {
            const int gr0 = row0 + wr * 64 + m * 16 + g * 4;
            const int bb = gr0 >> 11, t0 = gr0 & 2047;
#pragma unroll
            for (int n = 0; n < 2; ++n) {
                const int gc = gc0 + n * 16 + c;
                const int h = gc >> 6, dk = gc & 63;
                ushort4 u4;
                u4.x = f2bf(acc[m][n][0] + bv2[n]);
                u4.y = f2bf(acc[m][n][1] + bv2[n]);
                u4.z = f2bf(acc[m][n][2] + bv2[n]);
                u4.w = f2bf(acc[m][n][3] + bv2[n]);
                *(ushort4*)&VTo[((size_t)(bb * NHEADS + h) * DK + dk) * TS + t0] = u4;
            }
        }
    }
}

// ---------------------------------------------------------------------------
// Output projection: fp32 out [M][DMODEL].
// ---------------------------------------------------------------------------
__global__ __launch_bounds__(256) void gemm_out_kernel(
    const ushort_t* __restrict__ A, const ushort_t* __restrict__ W,
    const float* __restrict__ bias, float* __restrict__ Cout)
{
    __shared__ ushort_t Asm[2][4096];
    __shared__ ushort_t Bsm[2][2048];

    const int tid = threadIdx.x, w = tid >> 6, lane = tid & 63;
    const int c = lane & 15, g = lane >> 4;
    const int wr = w >> 1, wc = w & 1;
    const int row0 = blockIdx.y * 128, col0 = blockIdx.x * 64;

    f32x4 acc[4][2];
#pragma unroll
    for (int m = 0; m < 4; ++m)
#pragma unroll
        for (int n = 0; n < 2; ++n) acc[m][n] = (f32x4){0.f, 0.f, 0.f, 0.f};

    gemm_body(A, W, Asm, Bsm, acc, row0, col0, w, lane);

    const int gc0 = col0 + wc * 32;
    const float bv2[2] = {bias[gc0 + c], bias[gc0 + 16 + c]};
#pragma unroll
    for (int m = 0; m < 4; ++m)
#pragma unroll
        for (int n = 0; n < 2; ++n) {
            const int gc = gc0 + n * 16 + c;
#pragma unroll
            for (int r = 0; r < 4; ++r) {
                const int gr = row0 + wr * 64 + m * 16 + g * 4 + r;
                Cout[(size_t)gr * DMODEL + gc] = acc[m][n][r] + bv2[n];
            }
        }
}

// ---------------------------------------------------------------------------
// Flash attention, swapped-operand MFMA. 4 waves x 16 q-rows, KV tiles of 64.
// Q pre-scaled by 0.125. K [B,H,T,DK], V^T [B,H,DK,T]. Per lane: q = lane&15.
// K/V^T staged via global_load_lds with pre-swizzled source (XOR (row&7) on
// 16B granule); double-buffered, ONE barrier per tile. P via per-wave LDS.
// ---------------------------------------------------------------------------
__global__ __launch_bounds__(256) void attn_bf16_kernel(
    const ushort_t* __restrict__ Q, const ushort_t* __restrict__ K,
    const ushort_t* __restrict__ VT, ushort_t* __restrict__ ctx)
{
    __shared__ ushort_t Ks[2][64 * 64];   // [s][d] swizzled, 8KB each
    __shared__ ushort_t Vt[2][64 * 64];   // [d][s] swizzled
    __shared__ ushort_t Ps[4][16 * 64];   // per-wave [q][s] swizzled

    const int tid = threadIdx.x;
    const int w = tid >> 6, lane = tid & 63;
    const int c = lane & 15, g = lane >> 4;
    // XCD-clustered decode: all 32 q-blocks of one bh on one XCD
    const int sid = blockIdx.x;
    const int bh = (sid & 7) + ((sid >> 8) << 3);
    const int qb = (sid >> 3) & 31;
    const int q0 = qb << 6;
    const size_t base = (size_t)bh * TS * DK;
    const ushort_t* Qp = Q + base;
    const ushort_t* Kp = K + base;
    const ushort_t* VTp = VT + base;  // [DK][TS]

    // staging source (pre-swizzled): lane -> row w*16+lrow8, granule lc16^lrow8
    const int lrow8 = lane >> 3;
    const int lc16 = lane & 7;
    const int scol = (lc16 ^ lrow8) << 3;  // in ushorts
    const ushort_t* Kg = Kp + (size_t)(w * 16 + lrow8) * DK + scol;
    const ushort_t* Vg = VTp + (size_t)(w * 16 + lrow8) * TS + scol;

#define STAGE(buf, s0_) do { \
    gload_lds16(Kg + (size_t)(s0_) * DK, &Ks[buf][(w * 16) * 64]); \
    gload_lds16(Kg + (size_t)((s0_) + 8) * DK, &Ks[buf][(w * 16 + 8) * 64]); \
    gload_lds16(Vg + (s0_), &Vt[buf][(w * 16) * 64]); \
    gload_lds16(Vg + (s0_) + 8 * TS, &Vt[buf][(w * 16 + 8) * 64]); \
} while (0)

    // Q fragments (B-operand): lane (c,g) holds Q[q=c][d = ch*32 + g*8 + j]
    bf16x8 qa[2];
    {
        const ushort_t* qrow = Qp + (size_t)(q0 + w * 16 + c) * DK;
        qa[0] = *(const bf16x8*)(qrow + g * 8);
        qa[1] = *(const bf16x8*)(qrow + 32 + g * 8);
    }

    float m_i = -1e30f, l_i = 0.f;
    f32x4 o[4];
#pragma unroll
    for (int df = 0; df < 4; ++df) o[df] = (f32x4){0.f, 0.f, 0.f, 0.f};

    const int cs = (c & 7) << 4;  // row-based byte XOR (rows ≡ c mod 8)
    char* Pw = (char*)&Ps[w][0] + c * 128;

    STAGE(0, 0);
    __syncthreads();
    int cur = 0;

    for (int s0 = 0; s0 < TS; s0 += 64) {
        if (s0 + 64 < TS) STAGE(cur ^ 1, s0 + 64);

        const char* Kb = (const char*)&Ks[cur][0];
        const char* Vb = (const char*)&Vt[cur][0];

        // S^T = K @ Q^T : lane holds S[q=c][key = fc*16 + g*4 + r]
        f32x4 sf[4];
#pragma unroll
        for (int fc = 0; fc < 4; ++fc) {
            sf[fc] = (f32x4){0.f, 0.f, 0.f, 0.f};
#pragma unroll
            for (int ch = 0; ch < 2; ++ch) {
                const bf16x8 kb = *(const bf16x8*)(Kb + (fc * 16 + c) * 128 +
                                                   ((ch * 64 + g * 16) ^ cs));
                sf[fc] = __builtin_amdgcn_mfma_f32_16x16x32_bf16(kb, qa[ch], sf[fc],
                                                                 0, 0, 0);
            }
        }

        // online softmax: in-lane max over 16, then 2 cross-g shuffles
        float m0 = fmaxf(fmaxf(sf[0][0], sf[0][1]), fmaxf(sf[0][2], sf[0][3]));
        float m1 = fmaxf(fmaxf(sf[1][0], sf[1][1]), fmaxf(sf[1][2], sf[1][3]));
        float m2 = fmaxf(fmaxf(sf[2][0], sf[2][1]), fmaxf(sf[2][2], sf[2][3]));
        float m3 = fmaxf(fmaxf(sf[3][0], sf[3][1]), fmaxf(sf[3][2], sf[3][3]));
        float mt = fmaxf(fmaxf(m0, m1), fmaxf(m2, m3));
        mt = fmaxf(mt, __shfl_xor(mt, 16));
        mt = fmaxf(mt, __shfl_xor(mt, 32));

        const float mn = fmaxf(m_i, mt);
        const float fs = __expf(m_i - mn);
        m_i = mn;

        float p[4][4];
        float rs = 0.f;
#pragma unroll
        for (int fc = 0; fc < 4; ++fc)
#pragma unroll
            for (int r = 0; r < 4; ++r) {
                p[fc][r] = __expf(sf[fc][r] - mn);
                rs += p[fc][r];
            }
        rs += __shfl_xor(rs, 16);
        rs += __shfl_xor(rs, 32);
        l_i = l_i * fs + rs;
#pragma unroll
        for (int df = 0; df < 4; ++df)
#pragma unroll
            for (int r = 0; r < 4; ++r) o[df][r] *= fs;

        // P -> per-wave LDS (packed bf16 via v_cvt_pk), same-wave in-order
#pragma unroll
        for (int fc = 0; fc < 4; ++fc) {
            uint2 u;
            u.x = cvt_pk_bf16(p[fc][0], p[fc][1]);
            u.y = cvt_pk_bf16(p[fc][2], p[fc][3]);
            *(uint2*)(Pw + ((fc * 32 + g * 8) ^ cs)) = u;
        }

        // O^T += V^T @ P^T : lane holds O[q=c][d = df*16 + g*4 + r]
#pragma unroll
        for (int ch = 0; ch < 2; ++ch) {
            const bf16x8 pb = *(const bf16x8*)(Pw + ((ch * 64 + g * 16) ^ cs));
#pragma unroll
            for (int df = 0; df < 4; ++df) {
                const bf16x8 vb = *(const bf16x8*)(Vb + (df * 16 + c) * 128 +
                                                   ((ch * 64 + g * 16) ^ cs));
                o[df] = __builtin_amdgcn_mfma_f32_16x16x32_bf16(vb, pb, o[df],
                                                                0, 0, 0);
            }
        }
        __syncthreads();
        cur ^= 1;
    }
#undef STAGE

    // epilogue: normalize + packed bf16 stores, ctx [B,T,DMODEL]
    const int bb = bh >> 4, h = bh & 15;
    const float inv = 1.0f / l_i;
    const int t = q0 + w * 16 + c;
    ushort_t* crow = ctx + ((size_t)(bb * TS + t) * DMODEL + h * 64 + g * 4);
#pragma unroll
    for (int df = 0; df < 4; ++df) {
        uint2 u;
        u.x = cvt_pk_bf16(o[df][0] * inv, o[df][1] * inv);
        u.y = cvt_pk_bf16(o[df][2] * inv, o[df][3] * inv);
        *(uint2*)(crow + df * 16) = u;
    }
}

// ---------------------------------------------------------------------------
extern "C" void kernel_launch(void* const* d_in, const int* in_sizes, int n_in,
                              void* d_out, int out_size, void* d_ws, size_t ws_size,
                              hipStream_t stream)
{
    const float* query  = (const float*)d_in[0];
    const float* key_in = (const float*)d_in[1];
    const float* value  = (const float*)d_in[2];
    const float* Wq = (const float*)d_in[3];
    const float* bq = (const float*)d_in[4];
    const float* Wk = (const float*)d_in[5];
    const float* bk = (const float*)d_in[6];
    const float* Wv = (const float*)d_in[7];
    const float* bv = (const float*)d_in[8];
    const float* Wo = (const float*)d_in[9];
    const float* bo = (const float*)d_in[10];

    ushort_t* W16 = (ushort_t*)d_ws;
    const size_t M1 = 1u << 20;
    ushort_t* qi  = W16;             // bf16 activations
    ushort_t* ki  = W16 + 4 * M1;
    ushort_t* vi  = W16 + 8 * M1;
    ushort_t* wqb = W16 + 12 * M1;   // bf16 weights
    ushort_t* wkb = W16 + 13 * M1;
    ushort_t* wvb = W16 + 14 * M1;
    ushort_t* wob = W16 + 15 * M1;
    ushort_t* Qp  = W16 + 16 * M1;   // Q [B,H,T,DK] (pre-scaled 0.125)
    ushort_t* Kp  = W16 + 20 * M1;   // K [B,H,T,DK]
    ushort_t* VpT = W16 + 24 * M1;   // V^T [B,H,DK,T]
    ushort_t* cb  = W16 + 28 * M1;   // ctx bf16 [B,T,DMODEL]

    cvt_all_kernel<<<16384, 256, 0, stream>>>(query, key_in, value,
                                              Wq, Wk, Wv, Wo, W16);

    gemm_qkv_kernel<<<dim3(16, 32, 3), 256, 0, stream>>>(
        qi, ki, vi, wqb, wkb, wvb, bq, bk, bv, Qp, Kp, VpT);

    attn_bf16_kernel<<<1024, 256, 0, stream>>>(Qp, Kp, VpT, cb);

    gemm_out_kernel<<<dim3(16, 32), 256, 0, stream>>>(cb, wob, bo, (float*)d_out);
}

// Round 4
// 248.446 us; speedup vs baseline: 5.6176x; 1.0741x over previous
//
#include <hip/hip_runtime.h>

typedef unsigned short ushort_t;
typedef __attribute__((ext_vector_type(8))) short bf16x8;
typedef __attribute__((ext_vector_type(4))) float f32x4;

#define DMODEL 1024
#define NHEADS 16
#define DK 64
#define BS 2
#define TS 2048
#define MROWS (BS * TS)  // 4096

__device__ __forceinline__ ushort_t f2bf(float x) {
    unsigned u = __float_as_uint(x);
    return (ushort_t)((u + 0x7FFFu + ((u >> 16) & 1u)) >> 16);  // RNE
}

__device__ __forceinline__ unsigned cvt_pk_bf16(float lo, float hi) {
    unsigned r;
    asm("v_cvt_pk_bf16_f32 %0, %1, %2" : "=v"(r) : "v"(lo), "v"(hi));
    return r;
}

__device__ __forceinline__ void gload_lds16(const void* g, void* l) {
    __builtin_amdgcn_global_load_lds(
        (const __attribute__((address_space(1))) unsigned*)g,
        (__attribute__((address_space(3))) unsigned*)l, 16, 0, 0);
}

// ---------------------------------------------------------------------------
// fp32 -> bf16 cast: 3 activations (4M each) + 4 weights (1M each).
// ---------------------------------------------------------------------------
__global__ __launch_bounds__(256) void cvt_all_kernel(
    const float* __restrict__ q, const float* __restrict__ k,
    const float* __restrict__ v, const float* __restrict__ wq,
    const float* __restrict__ wk, const float* __restrict__ wv,
    const float* __restrict__ wo, ushort_t* __restrict__ dst)
{
    const int i = blockIdx.x * 256 + threadIdx.x;  // float4 index
    const float4* s;
    int off;
    if (i < (1 << 20))      { s = (const float4*)q; off = i; }
    else if (i < (2 << 20)) { s = (const float4*)k; off = i - (1 << 20); }
    else if (i < (3 << 20)) { s = (const float4*)v; off = i - (2 << 20); }
    else {
        const int j = i - (3 << 20);
        const int w = j >> 18;
        off = j & 0x3FFFF;
        s = (w == 0) ? (const float4*)wq : (w == 1) ? (const float4*)wk
          : (w == 2) ? (const float4*)wv : (const float4*)wo;
    }
    const float4 x = s[off];
    ushort4 o;
    o.x = f2bf(x.x); o.y = f2bf(x.y); o.z = f2bf(x.z); o.w = f2bf(x.w);
    ((ushort4*)dst)[i] = o;
}

// ---------------------------------------------------------------------------
// GEMM core (m97 structure): 128x128 tile, 4 waves each 64x64 (4x4 frags),
// BK=32, double-buffered LDS, one barrier per k-step.
// ---------------------------------------------------------------------------
__device__ __forceinline__ void gemm_body128(
    const ushort_t* __restrict__ A, const ushort_t* __restrict__ W,
    ushort_t (&Asm)[2][4096], ushort_t (&Bsm)[2][4096],
    f32x4 (&acc)[4][4], int row0, int col0, int w, int lane)
{
    const int c = lane & 15, g = lane >> 4;
    const int wr = w >> 1, wc = w & 1;
    const int lr = lane >> 2;          // 0..15 staging row within 16-chunk
    const int lcb = (lane & 3) * 8;    // 16B chunk within 64B row
    const ushort_t* Ab = &A[(size_t)(row0 + w * 32 + lr) * DMODEL + lcb];
    const ushort_t* Wb = &W[(size_t)(col0 + w * 32 + lr) * DMODEL + lcb];

#define GSTAGE(buf, k0_) do { \
    gload_lds16(Ab + (k0_), &Asm[buf][(w * 32) * 32]); \
    gload_lds16(Ab + 16 * DMODEL + (k0_), &Asm[buf][(w * 32 + 16) * 32]); \
    gload_lds16(Wb + (k0_), &Bsm[buf][(w * 32) * 32]); \
    gload_lds16(Wb + 16 * DMODEL + (k0_), &Bsm[buf][(w * 32 + 16) * 32]); \
} while (0)

    GSTAGE(0, 0);
    __syncthreads();
    int cur = 0;
    for (int k0 = 0; k0 < DMODEL; k0 += 32) {
        if (k0 + 32 < DMODEL) GSTAGE(cur ^ 1, k0 + 32);
        bf16x8 a[4], b[4];
#pragma unroll
        for (int m = 0; m < 4; ++m)
            a[m] = *(const bf16x8*)&Asm[cur][(wr * 64 + m * 16 + c) * 32 + g * 8];
#pragma unroll
        for (int n = 0; n < 4; ++n)
            b[n] = *(const bf16x8*)&Bsm[cur][(wc * 64 + n * 16 + c) * 32 + g * 8];
        __builtin_amdgcn_s_setprio(1);
#pragma unroll
        for (int m = 0; m < 4; ++m)
#pragma unroll
            for (int n = 0; n < 4; ++n)
                acc[m][n] = __builtin_amdgcn_mfma_f32_16x16x32_bf16(
                    a[m], b[n], acc[m][n], 0, 0, 0);
        __builtin_amdgcn_s_setprio(0);
        __syncthreads();
        cur ^= 1;
    }
#undef GSTAGE
}

// ---------------------------------------------------------------------------
// Fused QKV projections. z=0: Q -> [B,H,T,DK] *0.125 ; z=1: K -> [B,H,T,DK];
// z=2: V -> transposed [B,H,DK,T] (packed 8B stores along t).
// ---------------------------------------------------------------------------
__global__ __launch_bounds__(256) void gemm_qkv_kernel(
    const ushort_t* __restrict__ Aq, const ushort_t* __restrict__ Ak,
    const ushort_t* __restrict__ Av, const ushort_t* __restrict__ Wq,
    const ushort_t* __restrict__ Wk, const ushort_t* __restrict__ Wv,
    const float* __restrict__ bq, const float* __restrict__ bk,
    const float* __restrict__ bv, ushort_t* __restrict__ Qo,
    ushort_t* __restrict__ Ko, ushort_t* __restrict__ VTo)
{
    __shared__ ushort_t Asm[2][4096];
    __shared__ ushort_t Bsm[2][4096];

    const int z = blockIdx.z;
    const ushort_t* A = (z == 0) ? Aq : (z == 1) ? Ak : Av;
    const ushort_t* W = (z == 0) ? Wq : (z == 1) ? Wk : Wv;
    const float* bias = (z == 0) ? bq : (z == 1) ? bk : bv;
    const float scale = (z == 0) ? 0.125f : 1.0f;

    const int tid = threadIdx.x, w = tid >> 6, lane = tid & 63;
    const int c = lane & 15, g = lane >> 4;
    const int wr = w >> 1, wc = w & 1;
    const int row0 = blockIdx.y * 128, col0 = blockIdx.x * 128;

    f32x4 acc[4][4];
#pragma unroll
    for (int m = 0; m < 4; ++m)
#pragma unroll
        for (int n = 0; n < 4; ++n) acc[m][n] = (f32x4){0.f, 0.f, 0.f, 0.f};

    gemm_body128(A, W, Asm, Bsm, acc, row0, col0, w, lane);

    const int gc0 = col0 + wc * 64;
    float bv4[4];
#pragma unroll
    for (int n = 0; n < 4; ++n) bv4[n] = bias[gc0 + n * 16 + c];

    if (z < 2) {
        ushort_t* O = (z == 0) ? Qo : Ko;
#pragma unroll
        for (int m = 0; m < 4; ++m)
#pragma unroll
            for (int n = 0; n < 4; ++n) {
                const int gc = gc0 + n * 16 + c;
                const int h = gc >> 6, dk = gc & 63;
#pragma unroll
                for (int r = 0; r < 4; ++r) {
                    const int gr = row0 + wr * 64 + m * 16 + g * 4 + r;
                    const int bb = gr >> 11, t = gr & 2047;
                    O[(((size_t)(bb * NHEADS + h) * TS + t) << 6) + dk] =
                        f2bf((acc[m][n][r] + bv4[n]) * scale);
                }
            }
    } else {
#pragma unroll
        for (int m = 0; m < 4; ++m) {
            const int gr0 = row0 + wr * 64 + m * 16 + g * 4;
            const int bb = gr0 >> 11, t0 = gr0 & 2047;
#pragma unroll
            for (int n = 0; n < 4; ++n) {
                const int gc = gc0 + n * 16 + c;
                const int h = gc >> 6, dk = gc & 63;
                ushort4 u4;
                u4.x = f2bf(acc[m][n][0] + bv4[n]);
                u4.y = f2bf(acc[m][n][1] + bv4[n]);
                u4.z = f2bf(acc[m][n][2] + bv4[n]);
                u4.w = f2bf(acc[m][n][3] + bv4[n]);
                *(ushort4*)&VTo[((size_t)(bb * NHEADS + h) * DK + dk) * TS + t0] = u4;
            }
        }
    }
}

// ---------------------------------------------------------------------------
// Output projection: fp32 out [M][DMODEL].
// ---------------------------------------------------------------------------
__global__ __launch_bounds__(256) void gemm_out_kernel(
    const ushort_t* __restrict__ A, const ushort_t* __restrict__ W,
    const float* __restrict__ bias, float* __restrict__ Cout)
{
    __shared__ ushort_t Asm[2][4096];
    __shared__ ushort_t Bsm[2][4096];

    const int tid = threadIdx.x, w = tid >> 6, lane = tid & 63;
    const int c = lane & 15, g = lane >> 4;
    const int wr = w >> 1, wc = w & 1;
    const int row0 = blockIdx.y * 128, col0 = blockIdx.x * 128;

    f32x4 acc[4][4];
#pragma unroll
    for (int m = 0; m < 4; ++m)
#pragma unroll
        for (int n = 0; n < 4; ++n) acc[m][n] = (f32x4){0.f, 0.f, 0.f, 0.f};

    gemm_body128(A, W, Asm, Bsm, acc, row0, col0, w, lane);

    const int gc0 = col0 + wc * 64;
    float bv4[4];
#pragma unroll
    for (int n = 0; n < 4; ++n) bv4[n] = bias[gc0 + n * 16 + c];
#pragma unroll
    for (int m = 0; m < 4; ++m)
#pragma unroll
        for (int n = 0; n < 4; ++n) {
            const int gc = gc0 + n * 16 + c;
#pragma unroll
            for (int r = 0; r < 4; ++r) {
                const int gr = row0 + wr * 64 + m * 16 + g * 4 + r;
                Cout[(size_t)gr * DMODEL + gc] = acc[m][n][r] + bv4[n];
            }
        }
}

// ---------------------------------------------------------------------------
// Flash attention, swapped-operand MFMA. 4 waves x 32 q-rows (QBLK=128),
// KV tiles of 64: K-frag and V-frag LDS reads amortized over 2 q-groups.
// Q pre-scaled 0.125. K [B,H,T,DK], V^T [B,H,DK,T]. Defer-max (THR=8).
// ---------------------------------------------------------------------------
__global__ __launch_bounds__(256) void attn_bf16_kernel(
    const ushort_t* __restrict__ Q, const ushort_t* __restrict__ K,
    const ushort_t* __restrict__ VT, ushort_t* __restrict__ ctx)
{
    __shared__ ushort_t Ks[2][64 * 64];   // [s][d] swizzled, 8KB each
    __shared__ ushort_t Vt[2][64 * 64];   // [d][s] swizzled
    __shared__ ushort_t Ps[4][32 * 64];   // per-wave [q][s] swizzled, 4KB each

    const int tid = threadIdx.x;
    const int w = tid >> 6, lane = tid & 63;
    const int c = lane & 15, g = lane >> 4;
    // XCD-clustered decode: the 16 q-blocks of one bh stay on one XCD
    const int sid = blockIdx.x;                    // 0..511
    const int bh = (sid & 7) | ((sid >> 7) << 3);  // 0..31
    const int qb = (sid >> 3) & 15;
    const int q0 = qb << 7;
    const size_t base = (size_t)bh * TS * DK;
    const ushort_t* Qp = Q + base;
    const ushort_t* Kp = K + base;
    const ushort_t* VTp = VT + base;  // [DK][TS]

    // staging source (pre-swizzled): lane -> row w*16+lrow8, granule lc16^lrow8
    const int lrow8 = lane >> 3;
    const int lc16 = lane & 7;
    const int scol = (lc16 ^ lrow8) << 3;  // in ushorts
    const ushort_t* Kg = Kp + (size_t)(w * 16 + lrow8) * DK + scol;
    const ushort_t* Vg = VTp + (size_t)(w * 16 + lrow8) * TS + scol;

#define STAGE(buf, s0_) do { \
    gload_lds16(Kg + (size_t)(s0_) * DK, &Ks[buf][(w * 16) * 64]); \
    gload_lds16(Kg + (size_t)((s0_) + 8) * DK, &Ks[buf][(w * 16 + 8) * 64]); \
    gload_lds16(Vg + (s0_), &Vt[buf][(w * 16) * 64]); \
    gload_lds16(Vg + (s0_) + 8 * TS, &Vt[buf][(w * 16 + 8) * 64]); \
} while (0)

    // Q fragments (B-operand): lane (c,g) holds Q[q][d = ch*32 + g*8 + j]
    bf16x8 qa[2][2];
#pragma unroll
    for (int qh = 0; qh < 2; ++qh) {
        const ushort_t* qrow = Qp + (size_t)(q0 + w * 32 + qh * 16 + c) * DK;
        qa[qh][0] = *(const bf16x8*)(qrow + g * 8);
        qa[qh][1] = *(const bf16x8*)(qrow + 32 + g * 8);
    }

    float m_i[2] = {-1e30f, -1e30f}, l_i[2] = {0.f, 0.f};
    f32x4 o[2][4];
#pragma unroll
    for (int qh = 0; qh < 2; ++qh)
#pragma unroll
        for (int df = 0; df < 4; ++df) o[qh][df] = (f32x4){0.f, 0.f, 0.f, 0.f};

    const int cs = (c & 7) << 4;  // row-based byte XOR (rows ≡ c mod 8)
    char* Pw0 = (char*)&Ps[w][0];

    STAGE(0, 0);
    __syncthreads();
    int cur = 0;

    for (int s0 = 0; s0 < TS; s0 += 64) {
        if (s0 + 64 < TS) STAGE(cur ^ 1, s0 + 64);

        const char* Kb = (const char*)&Ks[cur][0];
        const char* Vb = (const char*)&Vt[cur][0];

        // S^T = K @ Q^T : lane holds S[q][key = fc*16 + g*4 + r], q per qh
        f32x4 sf[2][4];
#pragma unroll
        for (int qh = 0; qh < 2; ++qh)
#pragma unroll
            for (int fc = 0; fc < 4; ++fc) sf[qh][fc] = (f32x4){0.f, 0.f, 0.f, 0.f};
#pragma unroll
        for (int fc = 0; fc < 4; ++fc) {
#pragma unroll
            for (int ch = 0; ch < 2; ++ch) {
                const bf16x8 kb = *(const bf16x8*)(Kb + (fc * 16 + c) * 128 +
                                                   ((ch * 64 + g * 16) ^ cs));
                __builtin_amdgcn_s_setprio(1);
                sf[0][fc] = __builtin_amdgcn_mfma_f32_16x16x32_bf16(kb, qa[0][ch],
                                                                    sf[0][fc], 0, 0, 0);
                sf[1][fc] = __builtin_amdgcn_mfma_f32_16x16x32_bf16(kb, qa[1][ch],
                                                                    sf[1][fc], 0, 0, 0);
                __builtin_amdgcn_s_setprio(0);
            }
        }

        // tile max per q-row (in-lane over 16, then 2 cross-g shuffles)
        float mt[2];
#pragma unroll
        for (int qh = 0; qh < 2; ++qh) {
            float a0 = fmaxf(fmaxf(sf[qh][0][0], sf[qh][0][1]),
                             fmaxf(sf[qh][0][2], sf[qh][0][3]));
            float a1 = fmaxf(fmaxf(sf[qh][1][0], sf[qh][1][1]),
                             fmaxf(sf[qh][1][2], sf[qh][1][3]));
            float a2 = fmaxf(fmaxf(sf[qh][2][0], sf[qh][2][1]),
                             fmaxf(sf[qh][2][2], sf[qh][2][3]));
            float a3 = fmaxf(fmaxf(sf[qh][3][0], sf[qh][3][1]),
                             fmaxf(sf[qh][3][2], sf[qh][3][3]));
            float m = fmaxf(fmaxf(a0, a1), fmaxf(a2, a3));
            m = fmaxf(m, __shfl_xor(m, 16));
            m = fmaxf(m, __shfl_xor(m, 32));
            mt[qh] = m;
        }

        // defer-max (T13): skip rescale when growth <= 8 on all rows
        const int defer = (mt[0] <= m_i[0] + 8.f) && (mt[1] <= m_i[1] + 8.f);
        if (!__all(defer)) {
#pragma unroll
            for (int qh = 0; qh < 2; ++qh) {
                const float mn = fmaxf(m_i[qh], mt[qh]);
                const float fs = __expf(m_i[qh] - mn);
                m_i[qh] = mn;
                l_i[qh] *= fs;
#pragma unroll
                for (int df = 0; df < 4; ++df)
#pragma unroll
                    for (int r = 0; r < 4; ++r) o[qh][df][r] *= fs;
            }
        }

        // P = exp(S - m), pack to bf16, per-wave LDS; l accumulate
#pragma unroll
        for (int qh = 0; qh < 2; ++qh) {
            char* Pw = Pw0 + (qh * 16 + c) * 128;
            float rs = 0.f;
#pragma unroll
            for (int fc = 0; fc < 4; ++fc) {
                float p0 = __expf(sf[qh][fc][0] - m_i[qh]);
                float p1 = __expf(sf[qh][fc][1] - m_i[qh]);
                float p2 = __expf(sf[qh][fc][2] - m_i[qh]);
                float p3 = __expf(sf[qh][fc][3] - m_i[qh]);
                rs += (p0 + p1) + (p2 + p3);
                uint2 u;
                u.x = cvt_pk_bf16(p0, p1);
                u.y = cvt_pk_bf16(p2, p3);
                *(uint2*)(Pw + ((fc * 32 + g * 8) ^ cs)) = u;
            }
            rs += __shfl_xor(rs, 16);
            rs += __shfl_xor(rs, 32);
            l_i[qh] += rs;
        }

        // O^T += V^T @ P^T : V frags shared across both q-groups
#pragma unroll
        for (int ch = 0; ch < 2; ++ch) {
            const bf16x8 pb0 = *(const bf16x8*)(Pw0 + c * 128 +
                                                ((ch * 64 + g * 16) ^ cs));
            const bf16x8 pb1 = *(const bf16x8*)(Pw0 + (16 + c) * 128 +
                                                ((ch * 64 + g * 16) ^ cs));
#pragma unroll
            for (int df = 0; df < 4; ++df) {
                const bf16x8 vb = *(const bf16x8*)(Vb + (df * 16 + c) * 128 +
                                                   ((ch * 64 + g * 16) ^ cs));
                __builtin_amdgcn_s_setprio(1);
                o[0][df] = __builtin_amdgcn_mfma_f32_16x16x32_bf16(vb, pb0,
                                                                   o[0][df], 0, 0, 0);
                o[1][df] = __builtin_amdgcn_mfma_f32_16x16x32_bf16(vb, pb1,
                                                                   o[1][df], 0, 0, 0);
                __builtin_amdgcn_s_setprio(0);
            }
        }
        __syncthreads();
        cur ^= 1;
    }
#undef STAGE

    // epilogue: normalize + packed bf16 stores, ctx [B,T,DMODEL]
    const int bb = bh >> 4, h = bh & 15;
#pragma unroll
    for (int qh = 0; qh < 2; ++qh) {
        const float inv = 1.0f / l_i[qh];
        const int t = q0 + w * 32 + qh * 16 + c;
        ushort_t* crow = ctx + ((size_t)(bb * TS + t) * DMODEL + h * 64 + g * 4);
#pragma unroll
        for (int df = 0; df < 4; ++df) {
            uint2 u;
            u.x = cvt_pk_bf16(o[qh][df][0] * inv, o[qh][df][1] * inv);
            u.y = cvt_pk_bf16(o[qh][df][2] * inv, o[qh][df][3] * inv);
            *(uint2*)(crow + df * 16) = u;
        }
    }
}

// ---------------------------------------------------------------------------
extern "C" void kernel_launch(void* const* d_in, const int* in_sizes, int n_in,
                              void* d_out, int out_size, void* d_ws, size_t ws_size,
                              hipStream_t stream)
{
    const float* query  = (const float*)d_in[0];
    const float* key_in = (const float*)d_in[1];
    const float* value  = (const float*)d_in[2];
    const float* Wq = (const float*)d_in[3];
    const float* bq = (const float*)d_in[4];
    const float* Wk = (const float*)d_in[5];
    const float* bk = (const float*)d_in[6];
    const float* Wv = (const float*)d_in[7];
    const float* bv = (const float*)d_in[8];
    const float* Wo = (const float*)d_in[9];
    const float* bo = (const float*)d_in[10];

    ushort_t* W16 = (ushort_t*)d_ws;
    const size_t M1 = 1u << 20;
    ushort_t* qi  = W16;             // bf16 activations
    ushort_t* ki  = W16 + 4 * M1;
    ushort_t* vi  = W16 + 8 * M1;
    ushort_t* wqb = W16 + 12 * M1;   // bf16 weights
    ushort_t* wkb = W16 + 13 * M1;
    ushort_t* wvb = W16 + 14 * M1;
    ushort_t* wob = W16 + 15 * M1;
    ushort_t* Qp  = W16 + 16 * M1;   // Q [B,H,T,DK] (pre-scaled 0.125)
    ushort_t* Kp  = W16 + 20 * M1;   // K [B,H,T,DK]
    ushort_t* VpT = W16 + 24 * M1;   // V^T [B,H,DK,T]
    ushort_t* cb  = W16 + 28 * M1;   // ctx bf16 [B,T,DMODEL]

    cvt_all_kernel<<<16384, 256, 0, stream>>>(query, key_in, value,
                                              Wq, Wk, Wv, Wo, W16);

    gemm_qkv_kernel<<<dim3(8, 32, 3), 256, 0, stream>>>(
        qi, ki, vi, wqb, wkb, wvb, bq, bk, bv, Qp, Kp, VpT);

    attn_bf16_kernel<<<512, 256, 0, stream>>>(Qp, Kp, VpT, cb);

    gemm_out_kernel<<<dim3(8, 32), 256, 0, stream>>>(cb, wob, bo, (float*)d_out);
}

// Round 6
// 248.120 us; speedup vs baseline: 5.6249x; 1.0013x over previous
//
#include <hip/hip_runtime.h>

typedef unsigned short ushort_t;
typedef __attribute__((ext_vector_type(8))) short bf16x8;
typedef __attribute__((ext_vector_type(4))) float f32x4;

#define DMODEL 1024
#define NHEADS 16
#define DK 64
#define BS 2
#define TS 2048
#define MROWS (BS * TS)  // 4096

// 0.125 * log2(e): folded into Q so attention uses raw v_exp_f32 (exp2)
#define QSCALE 0.1803368801111204f

__device__ __forceinline__ ushort_t f2bf(float x) {
    unsigned u = __float_as_uint(x);
    return (ushort_t)((u + 0x7FFFu + ((u >> 16) & 1u)) >> 16);  // RNE
}

__device__ __forceinline__ unsigned cvt_pk_bf16(float lo, float hi) {
    unsigned r;
    asm("v_cvt_pk_bf16_f32 %0, %1, %2" : "=v"(r) : "v"(lo), "v"(hi));
    return r;
}

__device__ __forceinline__ void gload_lds16(const void* g, void* l) {
    __builtin_amdgcn_global_load_lds(
        (const __attribute__((address_space(1))) unsigned*)g,
        (__attribute__((address_space(3))) unsigned*)l, 16, 0, 0);
}

// ---------------------------------------------------------------------------
// fp32 -> bf16 cast: 3 activations (4M each) + 4 weights (1M each).
// ---------------------------------------------------------------------------
__global__ __launch_bounds__(256) void cvt_all_kernel(
    const float* __restrict__ q, const float* __restrict__ k,
    const float* __restrict__ v, const float* __restrict__ wq,
    const float* __restrict__ wk, const float* __restrict__ wv,
    const float* __restrict__ wo, ushort_t* __restrict__ dst)
{
    const int i = blockIdx.x * 256 + threadIdx.x;  // float4 index
    const float4* s;
    int off;
    if (i < (1 << 20))      { s = (const float4*)q; off = i; }
    else if (i < (2 << 20)) { s = (const float4*)k; off = i - (1 << 20); }
    else if (i < (3 << 20)) { s = (const float4*)v; off = i - (2 << 20); }
    else {
        const int j = i - (3 << 20);
        const int w = j >> 18;
        off = j & 0x3FFFF;
        s = (w == 0) ? (const float4*)wq : (w == 1) ? (const float4*)wk
          : (w == 2) ? (const float4*)wv : (const float4*)wo;
    }
    const float4 x = s[off];
    ushort4 o;
    o.x = f2bf(x.x); o.y = f2bf(x.y); o.z = f2bf(x.z); o.w = f2bf(x.w);
    ((ushort4*)dst)[i] = o;
}

// ---------------------------------------------------------------------------
// GEMM core: 128x128 tile, 4 waves each 64x64 (4x4 frags), BK=32, dbuf LDS,
// one barrier per k-step.
// SWAP=false: acc = mfma(a, b)  -> lane holds C[t-frag=g4r][col=c]  (V^T path)
// SWAP=true : acc = mfma(b, a)  -> lane holds C[t=c][col-frag=g4r]  (packed
//             epilogue along output columns)
// ---------------------------------------------------------------------------
template <bool SWAP>
__device__ __forceinline__ void gemm_body128(
    const ushort_t* __restrict__ A, const ushort_t* __restrict__ W,
    ushort_t (&Asm)[2][4096], ushort_t (&Bsm)[2][4096],
    f32x4 (&acc)[4][4], int row0, int col0, int w, int lane)
{
    const int c = lane & 15, g = lane >> 4;
    const int wr = w >> 1, wc = w & 1;
    const int lr = lane >> 2;          // 0..15 staging row within 16-chunk
    const int lcb = (lane & 3) * 8;    // 16B chunk within 64B row
    const ushort_t* Ab = &A[(size_t)(row0 + w * 32 + lr) * DMODEL + lcb];
    const ushort_t* Wb = &W[(size_t)(col0 + w * 32 + lr) * DMODEL + lcb];

#define GSTAGE(buf, k0_) do { \
    gload_lds16(Ab + (k0_), &Asm[buf][(w * 32) * 32]); \
    gload_lds16(Ab + 16 * DMODEL + (k0_), &Asm[buf][(w * 32 + 16) * 32]); \
    gload_lds16(Wb + (k0_), &Bsm[buf][(w * 32) * 32]); \
    gload_lds16(Wb + 16 * DMODEL + (k0_), &Bsm[buf][(w * 32 + 16) * 32]); \
} while (0)

    GSTAGE(0, 0);
    __syncthreads();
    int cur = 0;
    for (int k0 = 0; k0 < DMODEL; k0 += 32) {
        if (k0 + 32 < DMODEL) GSTAGE(cur ^ 1, k0 + 32);
        bf16x8 a[4], b[4];
#pragma unroll
        for (int m = 0; m < 4; ++m)
            a[m] = *(const bf16x8*)&Asm[cur][(wr * 64 + m * 16 + c) * 32 + g * 8];
#pragma unroll
        for (int n = 0; n < 4; ++n)
            b[n] = *(const bf16x8*)&Bsm[cur][(wc * 64 + n * 16 + c) * 32 + g * 8];
        __builtin_amdgcn_s_setprio(1);
#pragma unroll
        for (int m = 0; m < 4; ++m)
#pragma unroll
            for (int n = 0; n < 4; ++n)
                acc[m][n] = SWAP
                    ? __builtin_amdgcn_mfma_f32_16x16x32_bf16(b[n], a[m],
                                                              acc[m][n], 0, 0, 0)
                    : __builtin_amdgcn_mfma_f32_16x16x32_bf16(a[m], b[n],
                                                              acc[m][n], 0, 0, 0);
        __builtin_amdgcn_s_setprio(0);
        __syncthreads();
        cur ^= 1;
    }
#undef GSTAGE
}

// ---------------------------------------------------------------------------
// Fused QKV. z=0: Q -> [B,H,T,DK] * (0.125*log2e), SWAP epilogue (uint2
// along dk). z=1: K -> [B,H,T,DK], SWAP. z=2: V -> [B,H,DK,T], non-SWAP
// (uint2 along t).
// ---------------------------------------------------------------------------
__global__ __launch_bounds__(256) void gemm_qkv_kernel(
    const ushort_t* __restrict__ Aq, const ushort_t* __restrict__ Ak,
    const ushort_t* __restrict__ Av, const ushort_t* __restrict__ Wq,
    const ushort_t* __restrict__ Wk, const ushort_t* __restrict__ Wv,
    const float* __restrict__ bq, const float* __restrict__ bk,
    const float* __restrict__ bv, ushort_t* __restrict__ Qo,
    ushort_t* __restrict__ Ko, ushort_t* __restrict__ VTo)
{
    __shared__ ushort_t Asm[2][4096];
    __shared__ ushort_t Bsm[2][4096];

    const int z = blockIdx.z;
    const ushort_t* A = (z == 0) ? Aq : (z == 1) ? Ak : Av;
    const ushort_t* W = (z == 0) ? Wq : (z == 1) ? Wk : Wv;
    const float* bias = (z == 0) ? bq : (z == 1) ? bk : bv;

    const int tid = threadIdx.x, w = tid >> 6, lane = tid & 63;
    const int c = lane & 15, g = lane >> 4;
    const int wr = w >> 1, wc = w & 1;
    const int row0 = blockIdx.y * 128, col0 = blockIdx.x * 128;

    f32x4 acc[4][4];
#pragma unroll
    for (int m = 0; m < 4; ++m)
#pragma unroll
        for (int n = 0; n < 4; ++n) acc[m][n] = (f32x4){0.f, 0.f, 0.f, 0.f};

    const int gc0 = col0 + wc * 64;

    if (z < 2) {
        gemm_body128<true>(A, W, Asm, Bsm, acc, row0, col0, w, lane);
        const float scale = (z == 0) ? QSCALE : 1.0f;
        ushort_t* O = (z == 0) ? Qo : Ko;
        float4 bias4[4];
#pragma unroll
        for (int n = 0; n < 4; ++n)
            bias4[n] = *(const float4*)&bias[gc0 + n * 16 + g * 4];
#pragma unroll
        for (int m = 0; m < 4; ++m) {
            const int gr = row0 + wr * 64 + m * 16 + c;
            const int bb = gr >> 11, t = gr & 2047;
#pragma unroll
            for (int n = 0; n < 4; ++n) {
                const int col = gc0 + n * 16 + g * 4;
                const int h = col >> 6, dk0 = col & 63;
                uint2 u;
                u.x = cvt_pk_bf16((acc[m][n][0] + bias4[n].x) * scale,
                                  (acc[m][n][1] + bias4[n].y) * scale);
                u.y = cvt_pk_bf16((acc[m][n][2] + bias4[n].z) * scale,
                                  (acc[m][n][3] + bias4[n].w) * scale);
                *(uint2*)&O[(((size_t)(bb * NHEADS + h) * TS + t) << 6) + dk0] = u;
            }
        }
    } else {
        gemm_body128<false>(A, W, Asm, Bsm, acc, row0, col0, w, lane);
        float bv4[4];
#pragma unroll
        for (int n = 0; n < 4; ++n) bv4[n] = bias[gc0 + n * 16 + c];
#pragma unroll
        for (int m = 0; m < 4; ++m) {
            const int gr0 = row0 + wr * 64 + m * 16 + g * 4;
            const int bb = gr0 >> 11, t0 = gr0 & 2047;
#pragma unroll
            for (int n = 0; n < 4; ++n) {
                const int gc = gc0 + n * 16 + c;
                const int h = gc >> 6, dk = gc & 63;
                uint2 u;
                u.x = cvt_pk_bf16(acc[m][n][0] + bv4[n],
                                  acc[m][n][1] + bv4[n]);
                u.y = cvt_pk_bf16(acc[m][n][2] + bv4[n],
                                  acc[m][n][3] + bv4[n]);
                *(uint2*)&VTo[((size_t)(bb * NHEADS + h) * DK + dk) * TS + t0] = u;
            }
        }
    }
}

// ---------------------------------------------------------------------------
// Output projection (SWAP): fp32 out [M][DMODEL], float4 stores.
// ---------------------------------------------------------------------------
__global__ __launch_bounds__(256) void gemm_out_kernel(
    const ushort_t* __restrict__ A, const ushort_t* __restrict__ W,
    const float* __restrict__ bias, float* __restrict__ Cout)
{
    __shared__ ushort_t Asm[2][4096];
    __shared__ ushort_t Bsm[2][4096];

    const int tid = threadIdx.x, w = tid >> 6, lane = tid & 63;
    const int c = lane & 15, g = lane >> 4;
    const int wr = w >> 1, wc = w & 1;
    const int row0 = blockIdx.y * 128, col0 = blockIdx.x * 128;

    f32x4 acc[4][4];
#pragma unroll
    for (int m = 0; m < 4; ++m)
#pragma unroll
        for (int n = 0; n < 4; ++n) acc[m][n] = (f32x4){0.f, 0.f, 0.f, 0.f};

    gemm_body128<true>(A, W, Asm, Bsm, acc, row0, col0, w, lane);

    const int gc0 = col0 + wc * 64;
    float4 bias4[4];
#pragma unroll
    for (int n = 0; n < 4; ++n)
        bias4[n] = *(const float4*)&bias[gc0 + n * 16 + g * 4];
#pragma unroll
    for (int m = 0; m < 4; ++m) {
        const int gr = row0 + wr * 64 + m * 16 + c;
#pragma unroll
        for (int n = 0; n < 4; ++n) {
            float4 cv;
            cv.x = acc[m][n][0] + bias4[n].x;
            cv.y = acc[m][n][1] + bias4[n].y;
            cv.z = acc[m][n][2] + bias4[n].z;
            cv.w = acc[m][n][3] + bias4[n].w;
            *(float4*)&Cout[(size_t)gr * DMODEL + gc0 + n * 16 + g * 4] = cv;
        }
    }
}

// ---------------------------------------------------------------------------
// Flash attention, swapped-operand MFMA. 4 waves x 32 q-rows (QBLK=128),
// KV tiles of 64. Q pre-scaled by 0.125*log2e -> exp2 softmax.
// K [B,H,T,DK], V^T [B,H,DK,T]. Defer-max (THR=8, log2 units).
// ---------------------------------------------------------------------------
__global__ __launch_bounds__(256) void attn_bf16_kernel(
    const ushort_t* __restrict__ Q, const ushort_t* __restrict__ K,
    const ushort_t* __restrict__ VT, ushort_t* __restrict__ ctx)
{
    __shared__ ushort_t Ks[2][64 * 64];   // [s][d] swizzled, 8KB each
    __shared__ ushort_t Vt[2][64 * 64];   // [d][s] swizzled
    __shared__ ushort_t Ps[4][32 * 64];   // per-wave [q][s] swizzled

    const int tid = threadIdx.x;
    const int w = tid >> 6, lane = tid & 63;
    const int c = lane & 15, g = lane >> 4;
    const int sid = blockIdx.x;                    // 0..511
    const int bh = (sid & 7) | ((sid >> 7) << 3);  // 0..31
    const int qb = (sid >> 3) & 15;
    const int q0 = qb << 7;
    const size_t base = (size_t)bh * TS * DK;
    const ushort_t* Qp = Q + base;
    const ushort_t* Kp = K + base;
    const ushort_t* VTp = VT + base;  // [DK][TS]

    const int lrow8 = lane >> 3;
    const int lc16 = lane & 7;
    const int scol = (lc16 ^ lrow8) << 3;  // pre-swizzled source granule
    const ushort_t* Kg = Kp + (size_t)(w * 16 + lrow8) * DK + scol;
    const ushort_t* Vg = VTp + (size_t)(w * 16 + lrow8) * TS + scol;

#define STAGE(buf, s0_) do { \
    gload_lds16(Kg + (size_t)(s0_) * DK, &Ks[buf][(w * 16) * 64]); \
    gload_lds16(Kg + (size_t)((s0_) + 8) * DK, &Ks[buf][(w * 16 + 8) * 64]); \
    gload_lds16(Vg + (s0_), &Vt[buf][(w * 16) * 64]); \
    gload_lds16(Vg + (s0_) + 8 * TS, &Vt[buf][(w * 16 + 8) * 64]); \
} while (0)

    bf16x8 qa[2][2];
#pragma unroll
    for (int qh = 0; qh < 2; ++qh) {
        const ushort_t* qrow = Qp + (size_t)(q0 + w * 32 + qh * 16 + c) * DK;
        qa[qh][0] = *(const bf16x8*)(qrow + g * 8);
        qa[qh][1] = *(const bf16x8*)(qrow + 32 + g * 8);
    }

    float m_i[2] = {-1e30f, -1e30f}, l_i[2] = {0.f, 0.f};
    f32x4 o[2][4];
#pragma unroll
    for (int qh = 0; qh < 2; ++qh)
#pragma unroll
        for (int df = 0; df < 4; ++df) o[qh][df] = (f32x4){0.f, 0.f, 0.f, 0.f};

    const int cs = (c & 7) << 4;
    char* Pw0 = (char*)&Ps[w][0];

    STAGE(0, 0);
    __syncthreads();
    int cur = 0;

    for (int s0 = 0; s0 < TS; s0 += 64) {
        if (s0 + 64 < TS) STAGE(cur ^ 1, s0 + 64);

        const char* Kb = (const char*)&Ks[cur][0];
        const char* Vb = (const char*)&Vt[cur][0];

        f32x4 sf[2][4];
#pragma unroll
        for (int qh = 0; qh < 2; ++qh)
#pragma unroll
            for (int fc = 0; fc < 4; ++fc) sf[qh][fc] = (f32x4){0.f, 0.f, 0.f, 0.f};
#pragma unroll
        for (int fc = 0; fc < 4; ++fc) {
#pragma unroll
            for (int ch = 0; ch < 2; ++ch) {
                const bf16x8 kb = *(const bf16x8*)(Kb + (fc * 16 + c) * 128 +
                                                   ((ch * 64 + g * 16) ^ cs));
                __builtin_amdgcn_s_setprio(1);
                sf[0][fc] = __builtin_amdgcn_mfma_f32_16x16x32_bf16(kb, qa[0][ch],
                                                                    sf[0][fc], 0, 0, 0);
                sf[1][fc] = __builtin_amdgcn_mfma_f32_16x16x32_bf16(kb, qa[1][ch],
                                                                    sf[1][fc], 0, 0, 0);
                __builtin_amdgcn_s_setprio(0);
            }
        }

        float mt[2];
#pragma unroll
        for (int qh = 0; qh < 2; ++qh) {
            float a0 = fmaxf(fmaxf(sf[qh][0][0], sf[qh][0][1]),
                             fmaxf(sf[qh][0][2], sf[qh][0][3]));
            float a1 = fmaxf(fmaxf(sf[qh][1][0], sf[qh][1][1]),
                             fmaxf(sf[qh][1][2], sf[qh][1][3]));
            float a2 = fmaxf(fmaxf(sf[qh][2][0], sf[qh][2][1]),
                             fmaxf(sf[qh][2][2], sf[qh][2][3]));
            float a3 = fmaxf(fmaxf(sf[qh][3][0], sf[qh][3][1]),
                             fmaxf(sf[qh][3][2], sf[qh][3][3]));
            float m = fmaxf(fmaxf(a0, a1), fmaxf(a2, a3));
            m = fmaxf(m, __shfl_xor(m, 16));
            m = fmaxf(m, __shfl_xor(m, 32));
            mt[qh] = m;
        }

        // defer-max (T13): values are log2-scale; p bounded by 2^8
        const int defer = (mt[0] <= m_i[0] + 8.f) && (mt[1] <= m_i[1] + 8.f);
        if (!__all(defer)) {
#pragma unroll
            for (int qh = 0; qh < 2; ++qh) {
                const float mn = fmaxf(m_i[qh], mt[qh]);
                const float fs = __builtin_amdgcn_exp2f(m_i[qh] - mn);
                m_i[qh] = mn;
                l_i[qh] *= fs;
#pragma unroll
                for (int df = 0; df < 4; ++df)
#pragma unroll
                    for (int r = 0; r < 4; ++r) o[qh][df][r] *= fs;
            }
        }

#pragma unroll
        for (int qh = 0; qh < 2; ++qh) {
            char* Pw = Pw0 + (qh * 16 + c) * 128;
            float rs = 0.f;
#pragma unroll
            for (int fc = 0; fc < 4; ++fc) {
                float p0 = __builtin_amdgcn_exp2f(sf[qh][fc][0] - m_i[qh]);
                float p1 = __builtin_amdgcn_exp2f(sf[qh][fc][1] - m_i[qh]);
                float p2 = __builtin_amdgcn_exp2f(sf[qh][fc][2] - m_i[qh]);
                float p3 = __builtin_amdgcn_exp2f(sf[qh][fc][3] - m_i[qh]);
                rs += (p0 + p1) + (p2 + p3);
                uint2 u;
                u.x = cvt_pk_bf16(p0, p1);
                u.y = cvt_pk_bf16(p2, p3);
                *(uint2*)(Pw + ((fc * 32 + g * 8) ^ cs)) = u;
            }
            rs += __shfl_xor(rs, 16);
            rs += __shfl_xor(rs, 32);
            l_i[qh] += rs;
        }

#pragma unroll
        for (int ch = 0; ch < 2; ++ch) {
            const bf16x8 pb0 = *(const bf16x8*)(Pw0 + c * 128 +
                                                ((ch * 64 + g * 16) ^ cs));
            const bf16x8 pb1 = *(const bf16x8*)(Pw0 + (16 + c) * 128 +
                                                ((ch * 64 + g * 16) ^ cs));
#pragma unroll
            for (int df = 0; df < 4; ++df) {
                const bf16x8 vb = *(const bf16x8*)(Vb + (df * 16 + c) * 128 +
                                                   ((ch * 64 + g * 16) ^ cs));
                __builtin_amdgcn_s_setprio(1);
                o[0][df] = __builtin_amdgcn_mfma_f32_16x16x32_bf16(vb, pb0,
                                                                   o[0][df], 0, 0, 0);
                o[1][df] = __builtin_amdgcn_mfma_f32_16x16x32_bf16(vb, pb1,
                                                                   o[1][df], 0, 0, 0);
                __builtin_amdgcn_s_setprio(0);
            }
        }
        __syncthreads();
        cur ^= 1;
    }
#undef STAGE

    const int bb = bh >> 4, h = bh & 15;
#pragma unroll
    for (int qh = 0; qh < 2; ++qh) {
        const float inv = 1.0f / l_i[qh];
        const int t = q0 + w * 32 + qh * 16 + c;
        ushort_t* crow = ctx + ((size_t)(bb * TS + t) * DMODEL + h * 64 + g * 4);
#pragma unroll
        for (int df = 0; df < 4; ++df) {
            uint2 u;
            u.x = cvt_pk_bf16(o[qh][df][0] * inv, o[qh][df][1] * inv);
            u.y = cvt_pk_bf16(o[qh][df][2] * inv, o[qh][df][3] * inv);
            *(uint2*)(crow + df * 16) = u;
        }
    }
}

// ---------------------------------------------------------------------------
extern "C" void kernel_launch(void* const* d_in, const int* in_sizes, int n_in,
                              void* d_out, int out_size, void* d_ws, size_t ws_size,
                              hipStream_t stream)
{
    const float* query  = (const float*)d_in[0];
    const float* key_in = (const float*)d_in[1];
    const float* value  = (const float*)d_in[2];
    const float* Wq = (const float*)d_in[3];
    const float* bq = (const float*)d_in[4];
    const float* Wk = (const float*)d_in[5];
    const float* bk = (const float*)d_in[6];
    const float* Wv = (const float*)d_in[7];
    const float* bv = (const float*)d_in[8];
    const float* Wo = (const float*)d_in[9];
    const float* bo = (const float*)d_in[10];

    ushort_t* W16 = (ushort_t*)d_ws;
    const size_t M1 = 1u << 20;
    ushort_t* qi  = W16;             // bf16 activations
    ushort_t* ki  = W16 + 4 * M1;
    ushort_t* vi  = W16 + 8 * M1;
    ushort_t* wqb = W16 + 12 * M1;   // bf16 weights
    ushort_t* wkb = W16 + 13 * M1;
    ushort_t* wvb = W16 + 14 * M1;
    ushort_t* wob = W16 + 15 * M1;
    ushort_t* Qp  = W16 + 16 * M1;   // Q [B,H,T,DK] (pre-scaled)
    ushort_t* Kp  = W16 + 20 * M1;   // K [B,H,T,DK]
    ushort_t* VpT = W16 + 24 * M1;   // V^T [B,H,DK,T]
    ushort_t* cb  = W16 + 28 * M1;   // ctx bf16 [B,T,DMODEL]

    cvt_all_kernel<<<16384, 256, 0, stream>>>(query, key_in, value,
                                              Wq, Wk, Wv, Wo, W16);

    gemm_qkv_kernel<<<dim3(8, 32, 3), 256, 0, stream>>>(
        qi, ki, vi, wqb, wkb, wvb, bq, bk, bv, Qp, Kp, VpT);

    attn_bf16_kernel<<<512, 256, 0, stream>>>(Qp, Kp, VpT, cb);

    gemm_out_kernel<<<dim3(8, 32), 256, 0, stream>>>(cb, wob, bo, (float*)d_out);
}